// Round 6
// baseline (241.878 us; speedup 1.0000x reference)
//
#include <hip/hip_runtime.h>
#include <stdint.h>
#include <math.h>

#define BB 8
#define SEQ 2048
#define CDIM 384
#define NH 6
#define HD 64
#define QKVN 1152

typedef __attribute__((ext_vector_type(8))) __bf16 bf16x8;
typedef __attribute__((ext_vector_type(4))) float f32x4;
typedef __attribute__((ext_vector_type(4))) unsigned short ushort4v;
typedef __attribute__((ext_vector_type(2))) unsigned int uint2v;

__device__ __forceinline__ unsigned short f2bf(float f) {
  unsigned int u = __float_as_uint(f);
  u += 0x7fffu + ((u >> 16) & 1u);
  return (unsigned short)(u >> 16);
}

// fp32 -> bf16 conversion, 4 elems/thread
__global__ void k_convert(const float* __restrict__ src, unsigned short* __restrict__ dst, int n4) {
  int i = blockIdx.x * blockDim.x + threadIdx.x;
  if (i >= n4) return;
  float4 f = reinterpret_cast<const float4*>(src)[i];
  ushort4v u;
  u.x = f2bf(f.x); u.y = f2bf(f.y); u.z = f2bf(f.z); u.w = f2bf(f.w);
  reinterpret_cast<ushort4v*>(dst)[i] = u;
}

__device__ __forceinline__ void gload_lds16(const unsigned short* g, unsigned short* l) {
  __builtin_amdgcn_global_load_lds((const __attribute__((address_space(1))) void*)g,
                                   (__attribute__((address_space(3))) void*)l, 16, 0, 0);
}

// C[M,Nc] = A[M,K] * Bm[Nc,K]^T   (both row-major bf16, K contiguous; m97 structure)
template<int OUT_F32>
__global__ __launch_bounds__(256, 2) void k_gemm_bt(
    const unsigned short* __restrict__ A, const unsigned short* __restrict__ Bm,
    unsigned short* __restrict__ Cb, float* __restrict__ Cf,
    const float* __restrict__ bias, int M, int Nc, int K)
{
  __shared__ unsigned short lA[128 * 32];
  __shared__ unsigned short lB[128 * 32];
  const int t = threadIdx.x;
  const int w = t >> 6, l = t & 63;
  const int wr = w >> 1, wc = w & 1;
  const int row0 = blockIdx.x * 128, col0 = blockIdx.y * 128;
  const f32x4 vzero = {0.f, 0.f, 0.f, 0.f};
  f32x4 acc[4][4];
#pragma unroll
  for (int m = 0; m < 4; ++m)
#pragma unroll
    for (int n = 0; n < 4; ++n) acc[m][n] = vzero;

  const int srow = w * 16 + (l >> 2);
  const int scol = (l & 3) * 8;
  const int lr = l & 15, kc = (l >> 4) * 8;

  for (int k0 = 0; k0 < K; k0 += 32) {
#pragma unroll
    for (int r = 0; r < 2; ++r) {
      gload_lds16(A + (size_t)(row0 + r * 64 + srow) * K + k0 + scol,
                  &lA[(r * 64 + srow) * 32 + scol]);
      gload_lds16(Bm + (size_t)(col0 + r * 64 + srow) * K + k0 + scol,
                  &lB[(r * 64 + srow) * 32 + scol]);
    }
    __syncthreads();
    bf16x8 af[4], bfr[4];
#pragma unroll
    for (int m = 0; m < 4; ++m)
      af[m] = *(const bf16x8*)&lA[(wr * 64 + m * 16 + lr) * 32 + kc];
#pragma unroll
    for (int n = 0; n < 4; ++n)
      bfr[n] = *(const bf16x8*)&lB[(wc * 64 + n * 16 + lr) * 32 + kc];
#pragma unroll
    for (int m = 0; m < 4; ++m)
#pragma unroll
      for (int n = 0; n < 4; ++n)
        acc[m][n] = __builtin_amdgcn_mfma_f32_16x16x32_bf16(af[m], bfr[n], acc[m][n], 0, 0, 0);
    __syncthreads();
  }

#pragma unroll
  for (int m = 0; m < 4; ++m) {
    const int row = row0 + wr * 64 + m * 16 + (l >> 4) * 4;
#pragma unroll
    for (int n = 0; n < 4; ++n) {
      const int col = col0 + wc * 64 + n * 16 + (l & 15);
      if (OUT_F32) {
        const float bv = bias[col];
#pragma unroll
        for (int j = 0; j < 4; ++j)
          Cf[(size_t)(row + j) * Nc + col] = acc[m][n][j] + bv;
      } else {
#pragma unroll
        for (int j = 0; j < 4; ++j)
          Cb[(size_t)(row + j) * Nc + col] = f2bf(acc[m][n][j]);
      }
    }
  }
}

// V slice of qkv (b,n,768 + h*64 + d) -> VT[(b*H+h), d, n]  (bf16)
__global__ void k_vtrans(const unsigned short* __restrict__ qkv, unsigned short* __restrict__ vt)
{
  __shared__ unsigned short tile[64][76];
  const int bh = blockIdx.x;
  const int b = bh / NH, h = bh - b * NH;
  const int n0 = blockIdx.y * 64;
  const int t = threadIdx.x;
  const int rr0 = t >> 4;
  const int c4 = (t & 15) * 4;
  const unsigned short* src = qkv + (size_t)(b * SEQ + n0) * QKVN + 2 * CDIM + h * HD;
#pragma unroll
  for (int rr = 0; rr < 4; ++rr) {
    int n = rr * 16 + rr0;
    ushort4v v = *(const ushort4v*)(src + (size_t)n * QKVN + c4);
    *(ushort4v*)&tile[n][c4] = v;
  }
  __syncthreads();
  unsigned short* dst = vt + (size_t)bh * HD * SEQ + n0;
#pragma unroll
  for (int rr = 0; rr < 4; ++rr) {
    int d = rr * 16 + rr0;
    ushort4v v;
    v.x = tile[c4 + 0][d];
    v.y = tile[c4 + 1][d];
    v.z = tile[c4 + 2][d];
    v.w = tile[c4 + 3][d];
    *(ushort4v*)(dst + (size_t)d * SEQ + c4) = v;
  }
}

// Flash attention v6: swapped QK^T, TWO 16-row q-tiles per wave sharing each
// K/V fragment read (halves LDS bytes per MFMA — LDS BW was the round-5 pipe).
// Grid 768 = 3 blocks/CU exact. Per-lane softmax, log2 domain, defer-rescale.
__global__ __launch_bounds__(256, 4) void k_attn(
    const unsigned short* __restrict__ qkv, const float* __restrict__ mask,
    const unsigned short* __restrict__ vt, unsigned short* __restrict__ aout)
{
  const int bid = blockIdx.x;
  const int b = bid & 7;            // batch -> XCD
  const int g2 = bid >> 3;          // 0..95
  const int h = g2 % NH;
  const int nt = g2 / NH;           // 0..15
  const int t = threadIdx.x;
  const int w = t >> 6, l = t & 63;
  const int gk = l >> 4, c = l & 15;
  const int q0 = nt * 128 + w * 16;   // tile0 rows; tile1 = q0+64

  __shared__ unsigned short lK[2][4096];
  __shared__ unsigned short lV[2][4096];
  __shared__ unsigned int lP[4][2][512];  // per-wave, per-tile 16q x 32 u32, XOR-swizzled
  unsigned int* prow0 = &lP[w][0][c * 32];
  unsigned int* prow1 = &lP[w][1][c * 32];

  const unsigned short* qb0 = qkv + (size_t)(b * SEQ + q0) * QKVN + h * HD;
  const unsigned short* qb1 = qb0 + (size_t)64 * QKVN;
  const unsigned short* kb = qkv + (size_t)(b * SEQ) * QKVN + CDIM + h * HD;
  const unsigned short* vb = vt + (size_t)(b * NH + h) * HD * SEQ;
  const float* mrow0 = mask + ((size_t)b * SEQ + q0 + c) * SEQ + 4 * gk;
  const float* mrow1 = mrow0 + (size_t)64 * SEQ;

  // staging: 256 threads x 16B x 2 issues = 64x64 bf16 tile; source pre-swizzled
  const int trow = t >> 3, tg = t & 7;
  const int glog = tg ^ (trow & 7);
  const size_t kSrc = (size_t)trow * QKVN + glog * 8;
  const size_t vSrc = (size_t)trow * SEQ + glog * 8;

  // fragment ds_read offsets (elems), read-side swizzle matches source
  const int fr0 = c * 64 + ((gk) ^ (c & 7)) * 8;
  const int fr1 = c * 64 + ((4 + gk) ^ (c & 7)) * 8;
  const int cx = (c & 7) << 2;        // P-slot XOR swizzle (bits 2-4: b64-safe)

  // Q as B'-frag (col=q=c, d-chunk gk*8), pre-scaled by rsqrt(D)*log2(e)
  bf16x8 qf00 = *(const bf16x8*)(qb0 + (size_t)c * QKVN + gk * 8);
  bf16x8 qf01 = *(const bf16x8*)(qb0 + (size_t)c * QKVN + 32 + gk * 8);
  bf16x8 qf10 = *(const bf16x8*)(qb1 + (size_t)c * QKVN + gk * 8);
  bf16x8 qf11 = *(const bf16x8*)(qb1 + (size_t)c * QKVN + 32 + gk * 8);
#pragma unroll
  for (int i = 0; i < 8; ++i) {
    qf00[i] = (__bf16)((float)qf00[i] * 0.18033688f);
    qf01[i] = (__bf16)((float)qf01[i] * 0.18033688f);
    qf10[i] = (__bf16)((float)qf10[i] * 0.18033688f);
    qf11[i] = (__bf16)((float)qf11[i] * 0.18033688f);
  }

  const f32x4 vzero = {0.f, 0.f, 0.f, 0.f};
  f32x4 acco0[4], acco1[4];
  float mreg0 = -INFINITY, asum0 = 0.f, mreg1 = -INFINITY, asum1 = 0.f;
#pragma unroll
  for (int dt = 0; dt < 4; ++dt) { acco0[dt] = vzero; acco1[dt] = vzero; }

  // prologue: stage kt=0 into buf 0
#pragma unroll
  for (int j = 0; j < 2; ++j) {
    gload_lds16(kb + (size_t)j * 32 * QKVN + kSrc, &lK[0][j * 2048 + t * 8]);
    gload_lds16(vb + (size_t)j * 32 * SEQ + vSrc, &lV[0][j * 2048 + t * 8]);
  }
  int buf = 0;

  for (int kt = 0; kt < SEQ; kt += 64) {
    const bool haveNext = (kt + 64 < SEQ);
    __syncthreads();
    if (haveNext) {
#pragma unroll
      for (int j = 0; j < 2; ++j) {
        gload_lds16(kb + (size_t)(kt + 64 + j * 32) * QKVN + kSrc, &lK[buf ^ 1][j * 2048 + t * 8]);
        gload_lds16(vb + (kt + 64) + (size_t)j * 32 * SEQ + vSrc, &lV[buf ^ 1][j * 2048 + t * 8]);
      }
    }

    // mask loads for this tile-pair (L2/L3 latency hides under QK MFMAs)
    float4 mk0[4], mk1[4];
#pragma unroll
    for (int j = 0; j < 4; ++j) {
      mk0[j] = *(const float4*)(mrow0 + kt + 16 * j);
      mk1[j] = *(const float4*)(mrow1 + kt + 16 * j);
    }

    // swapped QK^T for both tiles: K fragments read ONCE, used twice
    f32x4 s0[4], s1[4];
#pragma unroll
    for (int j = 0; j < 4; ++j) {
      bf16x8 kfa = *(const bf16x8*)&lK[buf][j * 1024 + fr0];
      bf16x8 kfb = *(const bf16x8*)&lK[buf][j * 1024 + fr1];
      s0[j] = __builtin_amdgcn_mfma_f32_16x16x32_bf16(kfa, qf00, vzero, 0, 0, 0);
      s0[j] = __builtin_amdgcn_mfma_f32_16x16x32_bf16(kfb, qf01, s0[j], 0, 0, 0);
      s1[j] = __builtin_amdgcn_mfma_f32_16x16x32_bf16(kfa, qf10, vzero, 0, 0, 0);
      s1[j] = __builtin_amdgcn_mfma_f32_16x16x32_bf16(kfb, qf11, s1[j], 0, 0, 0);
    }

    // masked log2-scores in place
#pragma unroll
    for (int j = 0; j < 4; ++j) {
      const float* m0 = (const float*)&mk0[j];
      const float* m1 = (const float*)&mk1[j];
#pragma unroll
      for (int r = 0; r < 4; ++r) {
        s0[j][r] = fmaf(m0[r], -144269.50f, s0[j][r]);
        s1[j][r] = fmaf(m1[r], -144269.50f, s1[j][r]);
      }
    }

    // per-lane max (own 16 keys) then cross-group; two independent chains
    float tm0 = fmaxf(fmaxf(fmaxf(s0[0][0], s0[0][1]), fmaxf(s0[0][2], s0[0][3])),
                      fmaxf(fmaxf(s0[1][0], s0[1][1]), fmaxf(s0[1][2], s0[1][3])));
    tm0 = fmaxf(tm0, fmaxf(fmaxf(fmaxf(s0[2][0], s0[2][1]), fmaxf(s0[2][2], s0[2][3])),
                           fmaxf(fmaxf(s0[3][0], s0[3][1]), fmaxf(s0[3][2], s0[3][3]))));
    float tm1 = fmaxf(fmaxf(fmaxf(s1[0][0], s1[0][1]), fmaxf(s1[0][2], s1[0][3])),
                      fmaxf(fmaxf(s1[1][0], s1[1][1]), fmaxf(s1[1][2], s1[1][3])));
    tm1 = fmaxf(tm1, fmaxf(fmaxf(fmaxf(s1[2][0], s1[2][1]), fmaxf(s1[2][2], s1[2][3])),
                           fmaxf(fmaxf(s1[3][0], s1[3][1]), fmaxf(s1[3][2], s1[3][3]))));
    tm0 = fmaxf(tm0, __shfl_xor(tm0, 16));
    tm0 = fmaxf(tm0, __shfl_xor(tm0, 32));
    tm1 = fmaxf(tm1, __shfl_xor(tm1, 16));
    tm1 = fmaxf(tm1, __shfl_xor(tm1, 32));

    // defer-rescale (T13, thr=8 in log2 domain), per tile
    if (__any(tm0 > mreg0 + 8.f)) {
      const float mn = fmaxf(mreg0, tm0);
      const float al = __builtin_amdgcn_exp2f(mreg0 - mn);
      mreg0 = mn;
      asum0 *= al;
      float alr[4];
#pragma unroll
      for (int r = 0; r < 4; ++r) alr[r] = __shfl(al, 20 * gk + r);
#pragma unroll
      for (int dt = 0; dt < 4; ++dt)
#pragma unroll
        for (int r = 0; r < 4; ++r) acco0[dt][r] *= alr[r];
    }
    if (__any(tm1 > mreg1 + 8.f)) {
      const float mn = fmaxf(mreg1, tm1);
      const float al = __builtin_amdgcn_exp2f(mreg1 - mn);
      mreg1 = mn;
      asum1 *= al;
      float alr[4];
#pragma unroll
      for (int r = 0; r < 4; ++r) alr[r] = __shfl(al, 20 * gk + r);
#pragma unroll
      for (int dt = 0; dt < 4; ++dt)
#pragma unroll
        for (int r = 0; r < 4; ++r) acco1[dt][r] *= alr[r];
    }

    // P = exp2(s - m) in place; row-sums
#pragma unroll
    for (int j = 0; j < 4; ++j)
#pragma unroll
      for (int r = 0; r < 4; ++r) {
        s0[j][r] = __builtin_amdgcn_exp2f(s0[j][r] - mreg0);
        s1[j][r] = __builtin_amdgcn_exp2f(s1[j][r] - mreg1);
      }
    float rs0 = ((s0[0][0] + s0[0][1]) + (s0[0][2] + s0[0][3]))
              + ((s0[1][0] + s0[1][1]) + (s0[1][2] + s0[1][3]))
              + ((s0[2][0] + s0[2][1]) + (s0[2][2] + s0[2][3]))
              + ((s0[3][0] + s0[3][1]) + (s0[3][2] + s0[3][3]));
    float rs1 = ((s1[0][0] + s1[0][1]) + (s1[0][2] + s1[0][3]))
              + ((s1[1][0] + s1[1][1]) + (s1[1][2] + s1[1][3]))
              + ((s1[2][0] + s1[2][1]) + (s1[2][2] + s1[2][3]))
              + ((s1[3][0] + s1[3][1]) + (s1[3][2] + s1[3][3]));
    rs0 += __shfl_xor(rs0, 16);
    rs0 += __shfl_xor(rs0, 32);
    rs1 += __shfl_xor(rs1, 16);
    rs1 += __shfl_xor(rs1, 32);
    asum0 += rs0;
    asum1 += rs1;

    // pack P to bf16x2, redistribute via swizzled LDS (b64 writes)
    __asm__ volatile("" ::: "memory");
#pragma unroll
    for (int j = 0; j < 4; ++j) {
      uint2v pr0, pr1;
      asm("v_cvt_pk_bf16_f32 %0, %1, %2" : "=v"(pr0.x) : "v"(s0[j][0]), "v"(s0[j][1]));
      asm("v_cvt_pk_bf16_f32 %0, %1, %2" : "=v"(pr0.y) : "v"(s0[j][2]), "v"(s0[j][3]));
      asm("v_cvt_pk_bf16_f32 %0, %1, %2" : "=v"(pr1.x) : "v"(s1[j][0]), "v"(s1[j][1]));
      asm("v_cvt_pk_bf16_f32 %0, %1, %2" : "=v"(pr1.y) : "v"(s1[j][2]), "v"(s1[j][3]));
      *(uint2v*)(prow0 + ((8 * j + 2 * gk) ^ cx)) = pr0;
      *(uint2v*)(prow1 + ((8 * j + 2 * gk) ^ cx)) = pr1;
    }
    __asm__ volatile("" ::: "memory");
    bf16x8 pf00 = *(const bf16x8*)(prow0 + ((4 * gk) ^ cx));
    bf16x8 pf01 = *(const bf16x8*)(prow0 + ((16 + 4 * gk) ^ cx));
    bf16x8 pf10 = *(const bf16x8*)(prow1 + ((4 * gk) ^ cx));
    bf16x8 pf11 = *(const bf16x8*)(prow1 + ((16 + 4 * gk) ^ cx));
    __asm__ volatile("" ::: "memory");

    // PV for both tiles: V fragments read ONCE, used twice
#pragma unroll
    for (int dt = 0; dt < 4; ++dt) {
      bf16x8 vf0 = *(const bf16x8*)&lV[buf][dt * 1024 + fr0];
      bf16x8 vf1 = *(const bf16x8*)&lV[buf][dt * 1024 + fr1];
      acco0[dt] = __builtin_amdgcn_mfma_f32_16x16x32_bf16(pf00, vf0, acco0[dt], 0, 0, 0);
      acco0[dt] = __builtin_amdgcn_mfma_f32_16x16x32_bf16(pf01, vf1, acco0[dt], 0, 0, 0);
      acco1[dt] = __builtin_amdgcn_mfma_f32_16x16x32_bf16(pf10, vf0, acco1[dt], 0, 0, 0);
      acco1[dt] = __builtin_amdgcn_mfma_f32_16x16x32_bf16(pf11, vf1, acco1[dt], 0, 0, 0);
    }
    buf ^= 1;
  }

  // normalize + store both tiles
  float inv0[4], inv1[4];
#pragma unroll
  for (int r = 0; r < 4; ++r) {
    inv0[r] = 1.0f / __shfl(asum0, 20 * gk + r);
    inv1[r] = 1.0f / __shfl(asum1, 20 * gk + r);
  }
  unsigned short* ob0 = aout + (size_t)(b * SEQ + q0) * CDIM + h * HD;
  unsigned short* ob1 = ob0 + (size_t)64 * CDIM;
#pragma unroll
  for (int r = 0; r < 4; ++r)
#pragma unroll
    for (int dt = 0; dt < 4; ++dt) {
      ob0[(size_t)(4 * gk + r) * CDIM + dt * 16 + c] = f2bf(acco0[dt][r] * inv0[r]);
      ob1[(size_t)(4 * gk + r) * CDIM + dt * 16 + c] = f2bf(acco1[dt][r] * inv1[r]);
    }
}

extern "C" void kernel_launch(void* const* d_in, const int* in_sizes, int n_in,
                              void* d_out, int out_size, void* d_ws, size_t ws_size,
                              hipStream_t stream) {
  (void)in_sizes; (void)n_in; (void)out_size; (void)ws_size;
  const float* x      = (const float*)d_in[0];
  const float* mask   = (const float*)d_in[2];
  const float* qkv_w  = (const float*)d_in[3];
  const float* proj_w = (const float*)d_in[4];
  const float* proj_b = (const float*)d_in[5];
  float* out = (float*)d_out;
  char* ws = (char*)d_ws;

  unsigned short* xb    = (unsigned short*)(ws + 0);         // x bf16:      12,582,912
  unsigned short* wqb   = (unsigned short*)(ws + 12582912);  // qkv_w bf16:     884,736
  unsigned short* wpb   = (unsigned short*)(ws + 13467648);  // proj_w bf16:    294,912
  unsigned short* qkvb  = (unsigned short*)(ws + 13762560);  // qkv bf16:    37,748,736
  unsigned short* vtb   = (unsigned short*)(ws + 51511296);  // V^T bf16:    12,582,912
  unsigned short* aoutb = (unsigned short*)(ws + 64094208);  // attn out:    12,582,912

  k_convert<<<6144, 256, 0, stream>>>(x, xb, 1572864);
  k_convert<<<432, 256, 0, stream>>>(qkv_w, wqb, 110592);
  k_convert<<<144, 256, 0, stream>>>(proj_w, wpb, 36864);
  k_gemm_bt<0><<<dim3(128, 9), 256, 0, stream>>>(xb, wqb, qkvb, nullptr, nullptr, 16384, 1152, 384);
  k_vtrans<<<dim3(48, 32), 256, 0, stream>>>(qkvb, vtb);
  k_attn<<<768, 256, 0, stream>>>(qkvb, mask, vtb, aoutb);
  k_gemm_bt<1><<<dim3(128, 3), 256, 0, stream>>>(aoutb, wpb, nullptr, out, proj_b, 16384, 384, 384);
}